// Round 5
// baseline (489.212 us; speedup 1.0000x reference)
//
#include <hip/hip_runtime.h>
#include <stdint.h>

#define N_SRCN 50000
#define N_DSTN 50000
#define NE     800000
#define HIDN   256
#define NEG    0.2f

typedef __attribute__((ext_vector_type(8)))  short short8;
typedef __attribute__((ext_vector_type(16))) float float16v;

__device__ __forceinline__ float bf2f(unsigned short u){
    union { unsigned u32; float f; } c; c.u32 = ((unsigned)u) << 16; return c.f;
}
__device__ __forceinline__ unsigned short f2bf(float f){
    union { float f; unsigned u; } c; c.f = f;
    unsigned r = c.u + 0x7fffu + ((c.u >> 16) & 1u);
    return (unsigned short)(r >> 16);
}
__device__ __forceinline__ unsigned pack2(float a, float b){
    return (unsigned)f2bf(a) | ((unsigned)f2bf(b) << 16);
}
__device__ __forceinline__ float4 ld4b(const unsigned short* p){
    uint2 u = *reinterpret_cast<const uint2*>(p);
    float4 r;
    r.x = bf2f((unsigned short)(u.x & 0xffff));
    r.y = bf2f((unsigned short)(u.x >> 16));
    r.z = bf2f((unsigned short)(u.y & 0xffff));
    r.w = bf2f((unsigned short)(u.y >> 16));
    return r;
}

// ---- pack weights, input-indexed (coalesced reads, scattered 2B writes) ----
// Wt2: [which(3)][cb(8)][kk(4)][lane(64)][8]   (49152)
// Wf : [g(3)][cb(8)][kk(32)][lane(64)][8]      (393216), K=512 = [Wih|Whh]
__global__ void pack_kernel(const float* __restrict__ Wsrc, const float* __restrict__ Wdst,
                            const float* __restrict__ Wres, const float* __restrict__ Wih,
                            const float* __restrict__ Whh,
                            unsigned short* __restrict__ Wt2,
                            unsigned short* __restrict__ Wf){
    int i = blockIdx.x * 256 + threadIdx.x;
    if (i < 49152){
        int which = i >> 14, j = i & 16383;          // j = k*256 + c
        int k = j >> 8, c = j & 255;
        const float* W = (which == 0) ? Wsrc : (which == 1 ? Wdst : Wres);
        float v = W[j];
        int off = which * 16384 + (c >> 5) * 2048 + (k >> 4) * 512
                + (((k >> 3) & 1) * 32 + (c & 31)) * 8 + (k & 7);
        Wt2[off] = f2bf(v);
    } else if (i < 49152 + 196608){
        int o = i - 49152;                            // Wih flat: (g*256+c)*256+k
        int row = o >> 8, k = o & 255;
        int g = row >> 8, c = row & 255;
        float v = Wih[o];
        int off = g * 131072 + (c >> 5) * 16384 + (k >> 4) * 512
                + (((k >> 3) & 1) * 32 + (c & 31)) * 8 + (k & 7);
        Wf[off] = f2bf(v);
    } else if (i < 49152 + 393216){
        int o = i - 49152 - 196608;                   // Whh
        int row = o >> 8, k = o & 255;
        int g = row >> 8, c = row & 255;
        float v = Whh[o];
        int off = g * 131072 + (c >> 5) * 16384 + (16 + (k >> 4)) * 512
                + (((k >> 3) & 1) * 32 + (c & 31)) * 8 + (k & 7);
        Wf[off] = f2bf(v);
    }
}

// ---- fused projection GEMM (K=64), z selects {src, dst, res} --------------
__global__ __launch_bounds__(256) void proj_kernel(
        const float* __restrict__ Agt, const float* __restrict__ Aag,
        const unsigned short* __restrict__ Wt2,
        const float* __restrict__ bsrc, const float* __restrict__ bdst,
        const float* __restrict__ bres,
        unsigned short* __restrict__ fs, unsigned short* __restrict__ fd,
        unsigned short* __restrict__ resb){
    __shared__ unsigned short As[64 * 72];
    __shared__ unsigned short Cs[64 * 72];
    int z = blockIdx.z;
    const float* A = (z == 0) ? Agt : Aag;
    const float* bias = (z == 0) ? bsrc : (z == 1 ? bdst : bres);
    unsigned short* out = (z == 0) ? fs : (z == 1 ? fd : resb);
    const unsigned short* Wb = Wt2 + z * 16384;
    int tid = threadIdx.x;
    int m0 = blockIdx.y * 64;
    #pragma unroll
    for (int i = 0; i < 4; ++i){
        int ci = tid + i * 256;
        int row = ci >> 4;
        int k4 = (ci & 15) << 2;
        int gr = m0 + row; if (gr >= N_SRCN) gr = N_SRCN - 1;
        float4 v = *reinterpret_cast<const float4*>(A + (size_t)gr * 64 + k4);
        unsigned short* dp = As + row * 72 + k4;
        dp[0] = f2bf(v.x); dp[1] = f2bf(v.y); dp[2] = f2bf(v.z); dp[3] = f2bf(v.w);
    }
    __syncthreads();
    int lane = tid & 63, w = tid >> 6;
    int l31 = lane & 31, half = lane >> 5;
    int msub = (w & 1) * 32;
    int cbw = blockIdx.x * 2 + (w >> 1);
    const unsigned short* bb = Wb + cbw * 2048 + lane * 8;
    const unsigned short* ap = As + (msub + l31) * 72 + half * 8;
    float16v acc = {0,0,0,0,0,0,0,0,0,0,0,0,0,0,0,0};
    #pragma unroll
    for (int ks = 0; ks < 4; ++ks){
        short8 a = *reinterpret_cast<const short8*>(ap + ks * 16);
        short8 b = *reinterpret_cast<const short8*>(bb + ks * 512);
        acc = __builtin_amdgcn_mfma_f32_32x32x16_bf16(a, b, acc, 0, 0, 0);
    }
    float bv = bias[cbw * 32 + l31];
    int ccol = (w >> 1) * 32 + l31;
    #pragma unroll
    for (int r = 0; r < 16; ++r){
        int row = (r & 3) + 8 * (r >> 2) + 4 * half + msub;
        Cs[row * 72 + ccol] = f2bf(acc[r] + bv);
    }
    __syncthreads();
    int srow = tid >> 2, chunk = tid & 3;
    int gr2 = m0 + srow;
    if (gr2 < N_SRCN){
        const uint4* sp = reinterpret_cast<const uint4*>(Cs + srow * 72 + chunk * 16);
        uint4* gp = reinterpret_cast<uint4*>(out + (size_t)gr2 * 256 + blockIdx.x * 64 + chunk * 16);
        gp[0] = sp[0];
        gp[1] = sp[1];
    }
}

// ---- edge CSR build -------------------------------------------------------
__global__ void degree_kernel(const int* __restrict__ dst, int* __restrict__ deg){
    int i = blockIdx.x * 256 + threadIdx.x;
    if (i < NE) atomicAdd(&deg[dst[i]], 1);
}

__global__ void scan1_kernel(const int* __restrict__ deg, int* __restrict__ bsum){
    __shared__ int s[256];
    int tid = threadIdx.x;
    int i = blockIdx.x * 256 + tid;
    s[tid] = (i < N_DSTN) ? deg[i] : 0;
    __syncthreads();
    #pragma unroll
    for (int off = 128; off; off >>= 1){
        if (tid < off) s[tid] += s[tid + off];
        __syncthreads();
    }
    if (tid == 0) bsum[blockIdx.x] = s[0];
}

__global__ void scan2_kernel(const int* __restrict__ bsum, int* __restrict__ boff){
    __shared__ int s[256];
    int tid = threadIdx.x;
    int v = (tid < 196) ? bsum[tid] : 0;
    s[tid] = v;
    __syncthreads();
    #pragma unroll
    for (int off = 1; off < 256; off <<= 1){
        int t = (tid >= off) ? s[tid - off] : 0;
        __syncthreads();
        s[tid] += t;
        __syncthreads();
    }
    if (tid < 196) boff[tid] = s[tid] - v;
}

__global__ void scan3_kernel(const int* __restrict__ deg, const int* __restrict__ boff,
                             int* __restrict__ ptr, int* __restrict__ cursor){
    __shared__ int s[256];
    int tid = threadIdx.x;
    int i = blockIdx.x * 256 + tid;
    int v = (i < N_DSTN) ? deg[i] : 0;
    s[tid] = v;
    __syncthreads();
    #pragma unroll
    for (int off = 1; off < 256; off <<= 1){
        int t = (tid >= off) ? s[tid - off] : 0;
        __syncthreads();
        s[tid] += t;
        __syncthreads();
    }
    int ex = s[tid] - v + boff[blockIdx.x];
    if (i < N_DSTN){ ptr[i] = ex; cursor[i] = ex; }
}

__global__ void scatter_kernel(const int* __restrict__ src, const int* __restrict__ dst,
                               int* __restrict__ cursor, int* __restrict__ csr){
    int i = blockIdx.x * 256 + threadIdx.x;
    if (i < NE){
        int d = dst[i];
        int pos = atomicAdd(&cursor[d], 1);
        csr[pos] = src[i];
    }
}

// ---- per-dst aggregation, 8-deep gather pipeline --------------------------
__global__ __launch_bounds__(256) void aggregate_kernel(
        const unsigned short* __restrict__ fs, const unsigned short* __restrict__ fd,
        const unsigned short* __restrict__ res, const float* __restrict__ attn,
        const int* __restrict__ ptr, const int* __restrict__ deg,
        const int* __restrict__ csr, unsigned short* __restrict__ x){
    int wv = threadIdx.x >> 6;
    int d = blockIdx.x * 4 + wv;
    if (d >= N_DSTN) return;
    int lane = threadIdx.x & 63;
    int c4 = lane * 4;
    float4 fdv = ld4b(fd + (size_t)d * 256 + c4);
    float4 at = *reinterpret_cast<const float4*>(attn + (lane >> 4) * 64 + (lane & 15) * 4);
    int p = ptr[d], dg = deg[d];
    float l = 0.f;
    float4 acc = make_float4(0.f, 0.f, 0.f, 0.f);
    for (int base = 0; base < dg; base += 64){
        int cnt = min(64, dg - base);
        int sreg = (lane < cnt) ? csr[p + base + lane] : 0;
        float4 buf[8];
        #pragma unroll
        for (int t = 0; t < 8; ++t)
            buf[t] = ld4b(fs + (size_t)__shfl(sreg, t & 63) * 256 + c4);
        for (int j = 0; j < cnt; j += 8){
            float4 nbuf[8];
            #pragma unroll
            for (int t = 0; t < 8; ++t)
                nbuf[t] = ld4b(fs + (size_t)__shfl(sreg, (j + 8 + t) & 63) * 256 + c4);
            #pragma unroll
            for (int t = 0; t < 8; ++t){
                float4 bv = buf[t];
                float ex = bv.x + fdv.x; ex = ex > 0.f ? ex : NEG * ex;
                float ey = bv.y + fdv.y; ey = ey > 0.f ? ey : NEG * ey;
                float ez = bv.z + fdv.z; ez = ez > 0.f ? ez : NEG * ez;
                float ew = bv.w + fdv.w; ew = ew > 0.f ? ew : NEG * ew;
                float part = ex * at.x + ey * at.y + ez * at.z + ew * at.w;
                part += __shfl_xor(part, 1);
                part += __shfl_xor(part, 2);
                part += __shfl_xor(part, 4);
                part += __shfl_xor(part, 8);
                float wgt = ((j + t) < cnt) ? __expf(part) : 0.f;
                l += wgt;
                acc.x = fmaf(wgt, bv.x, acc.x);
                acc.y = fmaf(wgt, bv.y, acc.y);
                acc.z = fmaf(wgt, bv.z, acc.z);
                acc.w = fmaf(wgt, bv.w, acc.w);
            }
            #pragma unroll
            for (int t = 0; t < 8; ++t) buf[t] = nbuf[t];
        }
    }
    float inv = (l > 0.f) ? 1.f / l : 0.f;
    float4 rv = ld4b(res + (size_t)d * 256 + c4);
    float xx = fmaxf(fmaf(acc.x, inv, rv.x), 0.f);
    float xy = fmaxf(fmaf(acc.y, inv, rv.y), 0.f);
    float xz = fmaxf(fmaf(acc.z, inv, rv.z), 0.f);
    float xw = fmaxf(fmaf(acc.w, inv, rv.w), 0.f);
    uint2 o;
    o.x = pack2(xx, xy);
    o.y = pack2(xz, xw);
    *reinterpret_cast<uint2*>(x + (size_t)d * 256 + c4) = o;
}

// ---- GRU v6: 128x64 block, wave=64rx32c (m=2), dbuf LDS, XCD swizzle ------
// grid 1568 = 8 XCD * 196; decode: xcd=id&7, r=id>>3, strip=xcd*49+(r>>2),
// cb-pair = r&3.  B demand per MFMA halves vs v4 (two m-frags share B frag).
__global__ __launch_bounds__(256, 2) void gru_kernel(
        const unsigned short* __restrict__ Xb,
        const float* __restrict__ H0, const unsigned short* __restrict__ Wf,
        const float* __restrict__ bih, const float* __restrict__ bhh,
        float* __restrict__ outH){
    __shared__ unsigned short As[2][128 * 72];
    int tid = threadIdx.x;
    int sid = blockIdx.x;
    int xcd = sid & 7, r_ = sid >> 3;
    int strip = xcd * 49 + (r_ >> 2);
    int cbp = r_ & 3;
    int m0 = strip << 7;
    int w = tid >> 6, lane = tid & 63;
    int l31 = lane & 31, half = lane >> 5;
    int whalf = w & 1;
    int cb = cbp * 2 + (w >> 1);
    int cg = cb * 32 + l31;
    const unsigned short* bb = Wf + (size_t)cb * 16384 + lane * 8;

    // staging coords (4 x 16B chunks per thread per 64-K chunk)
    int srow[4], sk8[4], sgr[4];
    #pragma unroll
    for (int i = 0; i < 4; ++i){
        int ci = tid + i * 256;
        srow[i] = ci >> 3;
        sk8[i]  = (ci & 7) << 3;
        int gr = m0 + srow[i]; if (gr >= N_DSTN) gr = N_DSTN - 1;
        sgr[i] = gr;
    }

    float16v ar0 = {0,0,0,0,0,0,0,0,0,0,0,0,0,0,0,0};
    float16v ar1 = ar0, az0 = ar0, az1 = ar0;
    float16v anx0 = ar0, anx1 = ar0, anh0 = ar0, anh1 = ar0;

    // prefetch chunk 0 (X, K window [0,64))
    uint4 pf[4];
    #pragma unroll
    for (int i = 0; i < 4; ++i)
        pf[i] = *reinterpret_cast<const uint4*>(Xb + (size_t)sgr[i] * 256 + sk8[i]);
    #pragma unroll
    for (int i = 0; i < 4; ++i)
        *reinterpret_cast<uint4*>(&As[0][srow[i] * 72 + sk8[i]]) = pf[i];
    __syncthreads();

    for (int c = 0; c < 8; ++c){
        // prefetch chunk c+1 into registers (overlaps with MFMA below)
        uint4 npf[4];
        if (c < 7){
            int cn = c + 1;
            if (cn < 4){
                #pragma unroll
                for (int i = 0; i < 4; ++i)
                    npf[i] = *reinterpret_cast<const uint4*>(
                        Xb + (size_t)sgr[i] * 256 + cn * 64 + sk8[i]);
            } else {
                #pragma unroll
                for (int i = 0; i < 4; ++i){
                    const float* hp = H0 + (size_t)sgr[i] * 256 + (cn - 4) * 64 + sk8[i];
                    float4 f0 = *reinterpret_cast<const float4*>(hp);
                    float4 f1 = *reinterpret_cast<const float4*>(hp + 4);
                    npf[i].x = pack2(f0.x, f0.y);
                    npf[i].y = pack2(f0.z, f0.w);
                    npf[i].z = pack2(f1.x, f1.y);
                    npf[i].w = pack2(f1.z, f1.w);
                }
            }
        }
        // MFMA on As[c&1]
        const unsigned short* ap = As[c & 1] + (whalf * 64 + l31) * 72 + half * 8;
        #pragma unroll
        for (int ks = 0; ks < 4; ++ks){
            int kk = c * 4 + ks;                   // 0..31
            short8 a0 = *reinterpret_cast<const short8*>(ap + ks * 16);
            short8 a1 = *reinterpret_cast<const short8*>(ap + 32 * 72 + ks * 16);
            short8 br = *reinterpret_cast<const short8*>(bb + (size_t)kk * 512);
            short8 bz = *reinterpret_cast<const short8*>(bb + 131072 + (size_t)kk * 512);
            short8 bn = *reinterpret_cast<const short8*>(bb + 262144 + (size_t)kk * 512);
            ar0 = __builtin_amdgcn_mfma_f32_32x32x16_bf16(a0, br, ar0, 0, 0, 0);
            ar1 = __builtin_amdgcn_mfma_f32_32x32x16_bf16(a1, br, ar1, 0, 0, 0);
            az0 = __builtin_amdgcn_mfma_f32_32x32x16_bf16(a0, bz, az0, 0, 0, 0);
            az1 = __builtin_amdgcn_mfma_f32_32x32x16_bf16(a1, bz, az1, 0, 0, 0);
            if (c < 4){
                anx0 = __builtin_amdgcn_mfma_f32_32x32x16_bf16(a0, bn, anx0, 0, 0, 0);
                anx1 = __builtin_amdgcn_mfma_f32_32x32x16_bf16(a1, bn, anx1, 0, 0, 0);
            } else {
                anh0 = __builtin_amdgcn_mfma_f32_32x32x16_bf16(a0, bn, anh0, 0, 0, 0);
                anh1 = __builtin_amdgcn_mfma_f32_32x32x16_bf16(a1, bn, anh1, 0, 0, 0);
            }
        }
        if (c < 7){
            #pragma unroll
            for (int i = 0; i < 4; ++i)
                *reinterpret_cast<uint4*>(&As[(c + 1) & 1][srow[i] * 72 + sk8[i]]) = npf[i];
        }
        __syncthreads();
    }

    float rb = bih[cg] + bhh[cg];
    float zb = bih[256 + cg] + bhh[256 + cg];
    float bin = bih[512 + cg], bhn = bhh[512 + cg];
    int mbase = m0 + whalf * 64;
#define GRU_EPI(VR, VZ, VNX, VNH, MSOFF)                                        \
    _Pragma("unroll")                                                           \
    for (int r = 0; r < 16; ++r){                                               \
        int m = mbase + (MSOFF) + (r & 3) + 8 * (r >> 2) + 4 * half;            \
        if (m < N_DSTN){                                                        \
            float h0v = H0[(size_t)m * 256 + cg];                               \
            float rr = 1.f / (1.f + __expf(-((VR)[r] + rb)));                   \
            float zz = 1.f / (1.f + __expf(-((VZ)[r] + zb)));                   \
            float nx = (VNX)[r] + bin + rr * ((VNH)[r] + bhn);                  \
            float tm = __expf(-2.f * fabsf(nx));                                \
            float nn = (1.f - tm) / (1.f + tm);                                 \
            nn = (nx >= 0.f) ? nn : -nn;                                        \
            outH[(size_t)m * 256 + cg] = (1.f - zz) * nn + zz * h0v;            \
        }                                                                       \
    }
    GRU_EPI(ar0, az0, anx0, anh0, 0)
    GRU_EPI(ar1, az1, anx1, anh1, 32)
#undef GRU_EPI
}

// ---- logits = h @ W_out + b_out (4-way ILP) -------------------------------
__global__ __launch_bounds__(256) void logits_kernel(
        const float* __restrict__ H, const float* __restrict__ Wout,
        const float* __restrict__ bout, float* __restrict__ outL){
    __shared__ float Hl[16 * 260];
    __shared__ float Wl[16 * 260];
    int tid = threadIdx.x;
    int m0 = blockIdx.x * 16;
    #pragma unroll
    for (int i = 0; i < 4; ++i){
        int ci = tid + i * 256;
        int row = ci >> 6;
        int c4 = (ci & 63) << 2;
        int gr = m0 + row; if (gr >= N_DSTN) gr = N_DSTN - 1;
        float4 v = *reinterpret_cast<const float4*>(H + (size_t)gr * 256 + c4);
        float* dp = Hl + row * 260 + c4;
        dp[0] = v.x; dp[1] = v.y; dp[2] = v.z; dp[3] = v.w;
    }
    #pragma unroll
    for (int i = 0; i < 16; ++i){
        int ci = tid + i * 256;
        int c = ci >> 4, j = ci & 15;
        Wl[j * 260 + c] = Wout[c * 16 + j];
    }
    __syncthreads();
    int row = tid >> 4, j = tid & 15;
    const float* hr = Hl + row * 260;
    const float* wr = Wl + j * 260;
    float a0 = bout[j], a1 = 0.f, a2 = 0.f, a3 = 0.f;
    #pragma unroll
    for (int c = 0; c < 256; c += 16){
        float4 h0v = *reinterpret_cast<const float4*>(hr + c);
        float4 w0v = *reinterpret_cast<const float4*>(wr + c);
        float4 h1v = *reinterpret_cast<const float4*>(hr + c + 4);
        float4 w1v = *reinterpret_cast<const float4*>(wr + c + 4);
        float4 h2v = *reinterpret_cast<const float4*>(hr + c + 8);
        float4 w2v = *reinterpret_cast<const float4*>(wr + c + 8);
        float4 h3v = *reinterpret_cast<const float4*>(hr + c + 12);
        float4 w3v = *reinterpret_cast<const float4*>(wr + c + 12);
        a0 = fmaf(h0v.x, w0v.x, fmaf(h0v.y, w0v.y, fmaf(h0v.z, w0v.z, fmaf(h0v.w, w0v.w, a0))));
        a1 = fmaf(h1v.x, w1v.x, fmaf(h1v.y, w1v.y, fmaf(h1v.z, w1v.z, fmaf(h1v.w, w1v.w, a1))));
        a2 = fmaf(h2v.x, w2v.x, fmaf(h2v.y, w2v.y, fmaf(h2v.z, w2v.z, fmaf(h2v.w, w2v.w, a2))));
        a3 = fmaf(h3v.x, w3v.x, fmaf(h3v.y, w3v.y, fmaf(h3v.z, w3v.z, fmaf(h3v.w, w3v.w, a3))));
    }
    int m = m0 + row;
    if (m < N_DSTN) outL[m * 16 + j] = (a0 + a1) + (a2 + a3);
}

extern "C" void kernel_launch(void* const* d_in, const int* in_sizes, int n_in,
                              void* d_out, int out_size, void* d_ws, size_t ws_size,
                              hipStream_t stream){
    const float* feat_gt = (const float*)d_in[0];
    const float* feat_ag = (const float*)d_in[1];
    const float* h0      = (const float*)d_in[2];
    const int*   e_src   = (const int*)d_in[3];
    const int*   e_dst   = (const int*)d_in[4];
    const float* W_src   = (const float*)d_in[5];
    const float* b_src   = (const float*)d_in[6];
    const float* W_dst   = (const float*)d_in[7];
    const float* b_dst   = (const float*)d_in[8];
    const float* attn    = (const float*)d_in[9];
    const float* W_res   = (const float*)d_in[10];
    const float* b_res   = (const float*)d_in[11];
    const float* W_ih    = (const float*)d_in[12];
    const float* W_hh    = (const float*)d_in[13];
    const float* b_ih    = (const float*)d_in[14];
    const float* b_hh    = (const float*)d_in[15];
    const float* W_out   = (const float*)d_in[16];
    const float* b_out   = (const float*)d_in[17];

    float* outL = (float*)d_out;
    float* outH = outL + (size_t)N_DSTN * 16;

    char* ws = (char*)d_ws;
    size_t off = 0;
    auto alloc = [&](size_t bytes) -> void* {
        void* p = ws + off; off = (off + bytes + 255) & ~(size_t)255; return p;
    };
    unsigned short* fs   = (unsigned short*)alloc((size_t)N_SRCN * 256 * 2);
    unsigned short* fd   = (unsigned short*)alloc((size_t)N_DSTN * 256 * 2);
    unsigned short* res  = (unsigned short*)alloc((size_t)N_DSTN * 256 * 2);
    unsigned short* xb   = (unsigned short*)alloc((size_t)N_DSTN * 256 * 2);
    unsigned short* Wt2  = (unsigned short*)alloc(49152 * 2);
    unsigned short* Wf   = (unsigned short*)alloc(393216 * 2);
    int* deg    = (int*)alloc(N_DSTN * 4);
    int* ptr    = (int*)alloc(N_DSTN * 4);
    int* cursor = (int*)alloc(N_DSTN * 4);
    int* csr    = (int*)alloc((size_t)NE * 4);
    int* bsum   = (int*)alloc(256 * 4);
    int* boff   = (int*)alloc(256 * 4);

    hipMemsetAsync(deg, 0, N_DSTN * 4, stream);
    pack_kernel<<<1728, 256, 0, stream>>>(W_src, W_dst, W_res, W_ih, W_hh, Wt2, Wf);

    proj_kernel<<<dim3(4, 782, 3), 256, 0, stream>>>(feat_gt, feat_ag, Wt2,
                                                     b_src, b_dst, b_res, fs, fd, res);

    degree_kernel<<<3125, 256, 0, stream>>>(e_dst, deg);
    scan1_kernel<<<196, 256, 0, stream>>>(deg, bsum);
    scan2_kernel<<<1, 256, 0, stream>>>(bsum, boff);
    scan3_kernel<<<196, 256, 0, stream>>>(deg, boff, ptr, cursor);
    scatter_kernel<<<3125, 256, 0, stream>>>(e_src, e_dst, cursor, csr);
    aggregate_kernel<<<12500, 256, 0, stream>>>(fs, fd, res, attn, ptr, deg, csr, xb);

    gru_kernel<<<1568, 256, 0, stream>>>(xb, h0, Wf, b_ih, b_hh, outH);
    logits_kernel<<<3125, 256, 0, stream>>>(outH, W_out, b_out, outL);
}